// Round 2
// baseline (1220.894 us; speedup 1.0000x reference)
//
#include <hip/hip_runtime.h>
#include <math.h>

// Problem constants (match reference)
constexpr int B_  = 4096;
constexpr int T_  = 200;
constexpr int D_  = 64;
constexpr int H1_ = 80;
constexpr int H2_ = 40;
constexpr int NT  = 256;               // threads per block
constexpr float NEG_INF_F = -4294967295.0f;  // float32(-2^32+1)

// ---------------------------------------------------------------------------
// Fold weights into workspace.
// wf  [c=0..7][n=0..79][16]: j<8 -> Wk[d=c*8+j][n] = W1[(64+d)*80+n]-W1[(128+d)*80+n]
//                            j>=8 -> Wqk[d][n]     = W1[(192+d)*80+n]
// w2t [m=0..39][n=0..79] = W2[n][m]
// wqf [d=0..63][n=0..79] = W1[d][n] + W1[(128+d)][n]   (q-side fold for hinit)
// ---------------------------------------------------------------------------
__global__ void fold_weights(const float* __restrict__ W1,
                             const float* __restrict__ W2,
                             float* __restrict__ wf,
                             float* __restrict__ w2t,
                             float* __restrict__ wqf) {
    int i = blockIdx.x * blockDim.x + threadIdx.x;
    if (i < 10240) {
        int j = i & 15;
        int n = (i >> 4) % 80;
        int c = i / 1280;
        int d = c * 8 + (j & 7);
        wf[i] = (j < 8) ? W1[(64 + d) * 80 + n] - W1[(128 + d) * 80 + n]
                        : W1[(192 + d) * 80 + n];
    } else if (i < 13440) {
        int k = i - 10240;
        int n = k % 80, m = k / 80;
        w2t[k] = W2[n * 40 + m];
    } else if (i < 18560) {
        int k = i - 13440;
        int n = k % 80, d = k / 80;
        wqf[k] = W1[d * 80 + n] + W1[(128 + d) * 80 + n];
    }
}

// hinit[b][n] = b1[n] + sum_d q[b][d] * wqf[d][n]
__global__ __launch_bounds__(256)
void hinit_kernel(const float* __restrict__ q,
                  const float* __restrict__ wqf,
                  const float* __restrict__ b1,
                  float* __restrict__ hinit) {
    int i = blockIdx.x * blockDim.x + threadIdx.x;
    if (i >= B_ * H1_) return;
    int b = i / H1_;
    int n = i - b * H1_;
    const float* qr = q + b * D_;
    float acc = b1[n];
    #pragma unroll 8
    for (int d = 0; d < D_; ++d) acc = fmaf(qr[d], wqf[d * 80 + n], acc);
    hinit[i] = acc;
}

// ---------------------------------------------------------------------------
// Main kernel: one block per batch row b; thread t handles key position t.
// __launch_bounds__(256,2): VGPR cap 256 -> h[80] stays in registers (round-1
// build capped at 72 VGPR and spilled h to scratch: 1131us vs ~180us floor).
// ---------------------------------------------------------------------------
__global__ __launch_bounds__(NT, 2)
void din_attn(const float* __restrict__ q,
              const float* __restrict__ keys,
              const int*   __restrict__ klen,
              const float* __restrict__ hinit_g,
              const float* __restrict__ wf,
              const float* __restrict__ w2t,
              const float* __restrict__ b2,
              const float* __restrict__ W3,
              const float* __restrict__ b3,
              float* __restrict__ out) {
    const int b   = blockIdx.x;
    const int tid = threadIdx.x;

    __shared__ float qs[D_];
    __shared__ float red[NT];        // logits, then attn weights
    __shared__ float part[4][D_];
    __shared__ float wred[8];

    if (tid < D_) qs[tid] = q[b * D_ + tid];
    __syncthreads();

    const int len = klen[b];
    const int t = tid;
    if (t < T_) {
        // init h from precomputed hinit (wave-uniform address -> s_load)
        float h[H1_];
        const float* hb = hinit_g + b * H1_;
        #pragma unroll
        for (int n = 0; n < H1_; ++n) h[n] = hb[n];

        const float* kr = keys + ((size_t)b * T_ + t) * D_;
        #pragma unroll 1
        for (int c = 0; c < 8; ++c) {
            float kv[8], qk[8];
            float4 a0 = *(const float4*)(kr + c * 8);
            float4 a1 = *(const float4*)(kr + c * 8 + 4);
            kv[0] = a0.x; kv[1] = a0.y; kv[2] = a0.z; kv[3] = a0.w;
            kv[4] = a1.x; kv[5] = a1.y; kv[6] = a1.z; kv[7] = a1.w;
            #pragma unroll
            for (int j = 0; j < 8; ++j) qk[j] = kv[j] * qs[c * 8 + j];

            const float* w = wf + c * 1280;   // wave-uniform -> s_load_dwordx16
            #pragma unroll
            for (int n = 0; n < H1_; ++n) {
                float acc = h[n];
                #pragma unroll
                for (int j = 0; j < 8; ++j) acc = fmaf(kv[j], w[n * 16 + j], acc);
                #pragma unroll
                for (int j = 0; j < 8; ++j) acc = fmaf(qk[j], w[n * 16 + 8 + j], acc);
                h[n] = acc;
            }
        }
        // sigmoid layer 1
        #pragma unroll
        for (int n = 0; n < H1_; ++n) h[n] = 1.0f / (1.0f + __expf(-h[n]));

        // layers 2+3 fused
        float logit = b3[0];
        #pragma unroll 1
        for (int m = 0; m < H2_; ++m) {
            float acc = b2[m];
            const float* w2 = w2t + m * 80;
            #pragma unroll
            for (int n = 0; n < H1_; ++n) acc = fmaf(h[n], w2[n], acc);
            float s = 1.0f / (1.0f + __expf(-acc));
            logit = fmaf(s, W3[m], logit);
        }

        float l = (t < len) ? logit : NEG_INF_F;
        red[t] = l * 0.125f;   // 1/sqrt(64)
    } else {
        red[t] = -INFINITY;    // padding rows excluded (exp -> 0)
    }
    __syncthreads();

    // block-wide softmax over red[0..255]
    float v = red[tid];
    float m = v;
    #pragma unroll
    for (int off = 32; off; off >>= 1) m = fmaxf(m, __shfl_xor(m, off));
    if ((tid & 63) == 0) wred[tid >> 6] = m;
    __syncthreads();
    m = fmaxf(fmaxf(wred[0], wred[1]), fmaxf(wred[2], wred[3]));
    float e = __expf(v - m);   // all-masked row -> exp(0)=1 each -> uniform
    float s = e;
    #pragma unroll
    for (int off = 32; off; off >>= 1) s += __shfl_xor(s, off);
    if ((tid & 63) == 0) wred[4 + (tid >> 6)] = s;
    __syncthreads();
    s = wred[4] + wred[5] + wred[6] + wred[7];
    red[tid] = e / s;          // attn weight (t >= 200 -> 0)
    __syncthreads();

    // out[b][d] = sum_t attn[t] * keys[b][t][d]
    {
        const int d = tid & 63, g = tid >> 6;
        float acc = 0.f;
        const float* kb = keys + (size_t)b * T_ * D_;
        for (int tt = g; tt < T_; tt += 4)
            acc = fmaf(red[tt], kb[tt * D_ + d], acc);
        part[g][d] = acc;
        __syncthreads();
        if (tid < D_)
            out[b * D_ + tid] = part[0][tid] + part[1][tid] + part[2][tid] + part[3][tid];
    }
}

extern "C" void kernel_launch(void* const* d_in, const int* in_sizes, int n_in,
                              void* d_out, int out_size, void* d_ws, size_t ws_size,
                              hipStream_t stream) {
    const float* q    = (const float*)d_in[0];
    const float* keys = (const float*)d_in[1];
    const int*   kl   = (const int*)d_in[2];
    const float* W1   = (const float*)d_in[3];
    const float* b1   = (const float*)d_in[4];
    const float* W2   = (const float*)d_in[5];
    const float* b2   = (const float*)d_in[6];
    const float* W3   = (const float*)d_in[7];
    const float* b3   = (const float*)d_in[8];

    float* wf    = (float*)d_ws;           // 10240 f (40 KB)
    float* w2t   = wf + 10240;             //  3200 f (12.8 KB)
    float* wqf   = w2t + 3200;             //  5120 f (20 KB)
    float* hinit = wqf + 5120;             // 327680 f (1.31 MB)

    fold_weights<<<(18560 + 255) / 256, 256, 0, stream>>>(W1, W2, wf, w2t, wqf);
    hinit_kernel<<<(B_ * H1_ + 255) / 256, 256, 0, stream>>>(q, wqf, b1, hinit);
    din_attn<<<B_, NT, 0, stream>>>(q, keys, kl, hinit, wf, w2t, b2, W3, b3,
                                    (float*)d_out);
}

// Round 3
// 207.626 us; speedup vs baseline: 5.8803x; 5.8803x over previous
//
#include <hip/hip_runtime.h>
#include <math.h>

constexpr int B_ = 4096, T_ = 200, D_ = 64, NT = 256;
constexpr float NEG_INF_F = -4294967295.0f;  // float32(-2^32+1)

typedef __attribute__((ext_vector_type(8))) __bf16 bf16x8;
typedef __attribute__((ext_vector_type(8))) short short8;
typedef __attribute__((ext_vector_type(4))) float f32x4;

__device__ __host__ inline unsigned short f2b_rne(float x) {
    unsigned u = __builtin_bit_cast(unsigned, x);
    u += 0x7FFF + ((u >> 16) & 1);
    return (unsigned short)(u >> 16);
}

__device__ inline bf16x8 pack8(float f0, float f1, float f2, float f3,
                               float f4, float f5, float f6, float f7) {
    short8 sv;
    sv[0] = (short)f2b_rne(f0); sv[1] = (short)f2b_rne(f1);
    sv[2] = (short)f2b_rne(f2); sv[3] = (short)f2b_rne(f3);
    sv[4] = (short)f2b_rne(f4); sv[5] = (short)f2b_rne(f5);
    sv[6] = (short)f2b_rne(f6); sv[7] = (short)f2b_rne(f7);
    return __builtin_bit_cast(bf16x8, sv);
}

// ---------------------------------------------------------------------------
// Fold weights into MFMA-fragment order (bf16).
// w1f[s=0..3][nt=0..4][lane][j=0..7]: B-frag of W1fold[128][80]
//   k = s*32+(lane>>4)*8+j; n = nt*16+(lane&15)
//   k<64: Wk = W1[64+k][n]-W1[128+k][n];  k>=64: Wqk = W1[192+(k-64)][n]
// w2f[s=0..2][nt=0..2][lane][j]: W2 padded to [96][48] with zeros
// wqf[d][n] = W1[d][n]+W1[128+d][n]  (f32, q-side fold for hinit)
// ---------------------------------------------------------------------------
__global__ void fold_weights(const float* __restrict__ W1,
                             const float* __restrict__ W2,
                             unsigned short* __restrict__ w1f,
                             unsigned short* __restrict__ w2f,
                             float* __restrict__ wqf) {
    int i = blockIdx.x * blockDim.x + threadIdx.x;
    if (i < 10240) {
        int j = i & 7, lane = (i >> 3) & 63, nt = (i >> 9) % 5, s = i / 2560;
        int k = s * 32 + (lane >> 4) * 8 + j;
        int n = nt * 16 + (lane & 15);
        float v = (k < 64) ? W1[(64 + k) * 80 + n] - W1[(128 + k) * 80 + n]
                           : W1[(192 + (k - 64)) * 80 + n];
        w1f[i] = f2b_rne(v);
    } else if (i < 14848) {
        int i2 = i - 10240;
        int j = i2 & 7, lane = (i2 >> 3) & 63, nt = (i2 >> 9) % 3, s = i2 / 1536;
        int k = s * 32 + (lane >> 4) * 8 + j;
        int n = nt * 16 + (lane & 15);
        float v = (k < 80 && n < 40) ? W2[k * 40 + n] : 0.f;
        w2f[i2] = f2b_rne(v);
    } else if (i < 19968) {
        int i3 = i - 14848;
        int n = i3 % 80, d = i3 / 80;
        wqf[i3] = W1[d * 80 + n] + W1[(128 + d) * 80 + n];
    }
}

// hinit[b][n] = b1[n] + sum_d q[b][d] * wqf[d][n]   (layer-1 C-init)
__global__ __launch_bounds__(256)
void hinit_kernel(const float* __restrict__ q, const float* __restrict__ wqf,
                  const float* __restrict__ b1, float* __restrict__ hinit) {
    int i = blockIdx.x * blockDim.x + threadIdx.x;
    if (i >= B_ * 80) return;
    int b = i / 80, n = i - b * 80;
    const float* qr = q + b * 64;
    float acc = b1[n];
    #pragma unroll 8
    for (int d = 0; d < 64; ++d) acc = fmaf(qr[d], wqf[d * 80 + n], acc);
    hinit[i] = acc;
}

// ---------------------------------------------------------------------------
// Main kernel: one block (4 waves) per batch row.
// Layer1: [208x128]@[128x80] bf16 MFMA, A built in-reg from keys, C-init=hinit.
// Layer2: [208x96]@[96x48] bf16 MFMA from h1 LDS (stride 104 = 2-way banks).
// Layer3 + mask via shfl; softmax + output = verified round-1 code.
// ---------------------------------------------------------------------------
__global__ __launch_bounds__(NT, 2)
void din_attn(const float* __restrict__ q, const float* __restrict__ keys,
              const int* __restrict__ klen, const float* __restrict__ hinit_g,
              const unsigned short* __restrict__ w1f,
              const unsigned short* __restrict__ w2f,
              const float* __restrict__ b2, const float* __restrict__ W3,
              const float* __restrict__ b3, float* __restrict__ out) {
    const int b = blockIdx.x, tid = threadIdx.x;
    const int l = tid & 63, wid = tid >> 6, g4 = l >> 4, ln = l & 15;

    __shared__ float qs[64];
    __shared__ float hin[80];
    __shared__ float w3s[48], b2s[48];
    __shared__ float red[256];
    __shared__ float part[4][64];
    __shared__ float wred[8];
    __shared__ unsigned short h1[208 * 104];   // 43.3 KB

    if (tid < 64) qs[tid] = q[b * 64 + tid];
    if (tid < 80) hin[tid] = hinit_g[b * 80 + tid];
    if (tid < 48) {
        w3s[tid] = (tid < 40) ? W3[tid] : 0.f;
        b2s[tid] = (tid < 40) ? b2[tid] : 0.f;
    }
    if (tid >= 200) red[tid] = -INFINITY;
    __syncthreads();

    const int len = klen[b];
    const float b3v = b3[0];

    // ---------------- Phase 1: layer-1 GEMM ----------------
    for (int base = wid; base < 13; base += 8) {
        const bool has2 = (base + 4 < 13);

        float4 kq[2][4];
        #pragma unroll
        for (int ti = 0; ti < 2; ++ti) {
            if (ti == 0 || has2) {
                int t = (base + 4 * ti) * 16 + ln;
                int tc = t < 200 ? t : 199;       // clamp: avoid OOB, rows masked later
                const float* row = keys + ((size_t)b * 200 + tc) * 64;
                kq[ti][0] = *(const float4*)(row + g4 * 8);
                kq[ti][1] = *(const float4*)(row + g4 * 8 + 4);
                kq[ti][2] = *(const float4*)(row + 32 + g4 * 8);
                kq[ti][3] = *(const float4*)(row + 32 + g4 * 8 + 4);
            }
        }
        float4 qv0  = *(const float4*)(qs + g4 * 8);
        float4 qv0b = *(const float4*)(qs + g4 * 8 + 4);
        float4 qv1  = *(const float4*)(qs + 32 + g4 * 8);
        float4 qv1b = *(const float4*)(qs + 32 + g4 * 8 + 4);

        f32x4 acc[2][5];
        #pragma unroll
        for (int ti = 0; ti < 2; ++ti)
            #pragma unroll
            for (int nt = 0; nt < 5; ++nt) {
                float iv = hin[nt * 16 + ln];
                acc[ti][nt] = (f32x4){iv, iv, iv, iv};
            }

        #pragma unroll
        for (int s = 0; s < 4; ++s) {
            bf16x8 bfr[5];
            #pragma unroll
            for (int nt = 0; nt < 5; ++nt)
                bfr[nt] = *(const bf16x8*)(w1f + ((s * 5 + nt) * 64 + l) * 8);
            #pragma unroll
            for (int ti = 0; ti < 2; ++ti) {
                if (ti == 1 && !has2) continue;
                float4 lo = (s & 1) ? kq[ti][2] : kq[ti][0];
                float4 hi = (s & 1) ? kq[ti][3] : kq[ti][1];
                bf16x8 av;
                if (s < 2) {
                    av = pack8(lo.x, lo.y, lo.z, lo.w, hi.x, hi.y, hi.z, hi.w);
                } else {
                    float4 ql = (s & 1) ? qv1 : qv0;
                    float4 qh = (s & 1) ? qv1b : qv0b;
                    av = pack8(lo.x * ql.x, lo.y * ql.y, lo.z * ql.z, lo.w * ql.w,
                               hi.x * qh.x, hi.y * qh.y, hi.z * qh.z, hi.w * qh.w);
                }
                #pragma unroll
                for (int nt = 0; nt < 5; ++nt)
                    acc[ti][nt] = __builtin_amdgcn_mfma_f32_16x16x32_bf16(
                        av, bfr[nt], acc[ti][nt], 0, 0, 0);
            }
        }

        // sigmoid -> h1 LDS (bf16); zero pad cols 80..95 for layer-2 K
        #pragma unroll
        for (int ti = 0; ti < 2; ++ti) {
            if (ti == 1 && !has2) continue;
            int tile = base + 4 * ti;
            #pragma unroll
            for (int nt = 0; nt < 5; ++nt)
                #pragma unroll
                for (int r = 0; r < 4; ++r) {
                    float sg = 1.f / (1.f + __expf(-acc[ti][nt][r]));
                    h1[(tile * 16 + g4 * 4 + r) * 104 + nt * 16 + ln] = f2b_rne(sg);
                }
            #pragma unroll
            for (int r = 0; r < 4; ++r)
                h1[(tile * 16 + g4 * 4 + r) * 104 + 80 + ln] = 0;
        }
    }
    __syncthreads();

    // ---------------- Phase 2: layer-2 GEMM + layer-3 ----------------
    for (int tile = wid; tile < 13; tile += 4) {
        bf16x8 af[3];
        #pragma unroll
        for (int s = 0; s < 3; ++s)
            af[s] = *(const bf16x8*)(h1 + (tile * 16 + ln) * 104 + s * 32 + g4 * 8);
        f32x4 acc2[3];
        #pragma unroll
        for (int nt = 0; nt < 3; ++nt) {
            float iv = b2s[nt * 16 + ln];
            acc2[nt] = (f32x4){iv, iv, iv, iv};
        }
        #pragma unroll
        for (int s = 0; s < 3; ++s)
            #pragma unroll
            for (int nt = 0; nt < 3; ++nt) {
                bf16x8 bfr = *(const bf16x8*)(w2f + ((s * 3 + nt) * 64 + l) * 8);
                acc2[nt] = __builtin_amdgcn_mfma_f32_16x16x32_bf16(
                    af[s], bfr, acc2[nt], 0, 0, 0);
            }

        float w3v0 = w3s[ln], w3v1 = w3s[16 + ln], w3v2 = w3s[32 + ln];
        #pragma unroll
        for (int r = 0; r < 4; ++r) {
            float p = w3v0 / (1.f + __expf(-acc2[0][r]))
                    + w3v1 / (1.f + __expf(-acc2[1][r]))
                    + w3v2 / (1.f + __expf(-acc2[2][r]));
            p += __shfl_xor(p, 1); p += __shfl_xor(p, 2);
            p += __shfl_xor(p, 4); p += __shfl_xor(p, 8);
            if (ln == 0) {
                int trow = tile * 16 + g4 * 4 + r;
                if (trow < 200)
                    red[trow] = (trow < len) ? (p + b3v) * 0.125f
                                             : NEG_INF_F * 0.125f;
            }
        }
    }
    __syncthreads();

    // ---------------- softmax over red[0..255] (verified round-1) ----------
    float v = red[tid];
    float m = v;
    #pragma unroll
    for (int off = 32; off; off >>= 1) m = fmaxf(m, __shfl_xor(m, off));
    if ((tid & 63) == 0) wred[tid >> 6] = m;
    __syncthreads();
    m = fmaxf(fmaxf(wred[0], wred[1]), fmaxf(wred[2], wred[3]));
    float e = __expf(v - m);
    float s = e;
    #pragma unroll
    for (int off = 32; off; off >>= 1) s += __shfl_xor(s, off);
    if ((tid & 63) == 0) wred[4 + (tid >> 6)] = s;
    __syncthreads();
    s = wred[4] + wred[5] + wred[6] + wred[7];
    red[tid] = e / s;
    __syncthreads();

    // ---------------- output: out[b][d] = sum_t attn[t]*keys[b][t][d] ------
    {
        const int d = tid & 63, gg = tid >> 6;
        float acc = 0.f;
        const float* kb = keys + (size_t)b * T_ * D_;
        for (int tt = gg; tt < T_; tt += 4)
            acc = fmaf(red[tt], kb[tt * D_ + d], acc);
        part[gg][d] = acc;
        __syncthreads();
        if (tid < D_)
            out[b * D_ + tid] = part[0][tid] + part[1][tid] + part[2][tid] + part[3][tid];
    }
}

extern "C" void kernel_launch(void* const* d_in, const int* in_sizes, int n_in,
                              void* d_out, int out_size, void* d_ws, size_t ws_size,
                              hipStream_t stream) {
    const float* q    = (const float*)d_in[0];
    const float* keys = (const float*)d_in[1];
    const int*   kl   = (const int*)d_in[2];
    const float* W1   = (const float*)d_in[3];
    const float* b1   = (const float*)d_in[4];
    const float* W2   = (const float*)d_in[5];
    const float* b2   = (const float*)d_in[6];
    const float* W3   = (const float*)d_in[7];
    const float* b3   = (const float*)d_in[8];

    unsigned short* w1f = (unsigned short*)d_ws;            // 10240 bf16 (20.5 KB)
    unsigned short* w2f = w1f + 10240;                      //  4608 bf16 ( 9.2 KB)
    float* wqf   = (float*)((char*)d_ws + 32768);           //  5120 f32  (20.5 KB)
    float* hinit = wqf + 5120;                              // 327680 f32 (1.31 MB)

    fold_weights<<<(19968 + 255) / 256, 256, 0, stream>>>(W1, W2, w1f, w2f, wqf);
    hinit_kernel<<<(B_ * 80 + 255) / 256, 256, 0, stream>>>(q, wqf, b1, hinit);
    din_attn<<<B_, NT, 0, stream>>>(q, keys, kl, hinit, w1f, w2f, b2, W3, b3,
                                    (float*)d_out);
}